// Round 2
// baseline (1534.764 us; speedup 1.0000x reference)
//
#include <hip/hip_runtime.h>
#include <stdint.h>

#define T_LEN 512
#define NTOK  1536   // (1+NGRAM)*T
#define EMB   1024
#define NH    16
#define HD    64
#define BS    4

// ---------------------------------------------------------------------------
// Tiled fp32 GEMM  C[m,n] = sum_k A[m,k]*W[n,k] + bias[n]
// MODE 0: A=hidden (6144x1024), N=3584 = 3072 (in_proj) + 512 (rel_w).
//         Epilogue scatters q,k,v into fp32 [bh][tok][d] (q scaled by 1/8)
//         and rel-vals into fp32 [bh][tok][bucket(32)].
// MODE 1: A=attn_pre (6144x1024), W=out_w, N=1024 -> d_out fp32.
// Tile: 64x64, BK=16, 256 threads, 4x4 per thread, cols strided by 16
// (c = tx + 16j). LDS row stride 20 floats (80B): 16B-aligned, <=2-way
// bank aliasing (free on gfx950).
// ---------------------------------------------------------------------------
template<int MODE>
__global__ __launch_bounds__(256)
void gemm_k(const float* __restrict__ A,
            const float* __restrict__ W0,
            const float* __restrict__ W1,
            const float* __restrict__ B0,
            const float* __restrict__ B1,
            float* __restrict__ Qo,
            float* __restrict__ Ko,
            float* __restrict__ Vo,
            float* __restrict__ VALS,
            float* __restrict__ OUT)
{
  __shared__ float As[64*20];
  __shared__ float Ws[64*20];
  const int K = 1024;
  const int m0 = blockIdx.y * 64, n0 = blockIdx.x * 64;
  const int tid = threadIdx.x;
  const int tx = tid & 15, ty = tid >> 4;
  const int sr = tid >> 2, sc = (tid & 3) * 4;

  const float* arow = A + (size_t)(m0 + sr) * K + sc;
  const int nrow = n0 + sr;
  const float* wrow;
  if (MODE == 0)
    wrow = (nrow < 3072) ? (W0 + (size_t)nrow * K + sc)
                         : (W1 + (size_t)(nrow - 3072) * K + sc);
  else
    wrow = W0 + (size_t)nrow * K + sc;

  float acc[4][4];
  #pragma unroll
  for (int i=0;i<4;i++)
    #pragma unroll
    for (int j=0;j<4;j++) acc[i][j]=0.f;

  for (int k0 = 0; k0 < K; k0 += 16) {
    float4 av = *(const float4*)(arow + k0);
    float4 wv = *(const float4*)(wrow + k0);
    *(float4*)&As[sr*20 + sc] = av;
    *(float4*)&Ws[sr*20 + sc] = wv;
    __syncthreads();
    #pragma unroll
    for (int kk0 = 0; kk0 < 16; kk0 += 4) {
      float4 a4[4], b4[4];
      #pragma unroll
      for (int i=0;i<4;i++) a4[i] = *(const float4*)&As[(ty*4+i)*20 + kk0];
      #pragma unroll
      for (int j=0;j<4;j++) b4[j] = *(const float4*)&Ws[(tx+16*j)*20 + kk0];
      #pragma unroll
      for (int i=0;i<4;i++)
        #pragma unroll
        for (int j=0;j<4;j++){
          acc[i][j] += a4[i].x*b4[j].x;
          acc[i][j] += a4[i].y*b4[j].y;
          acc[i][j] += a4[i].z*b4[j].z;
          acc[i][j] += a4[i].w*b4[j].w;
        }
    }
    __syncthreads();
  }

  #pragma unroll
  for (int j=0;j<4;j++){
    const int col = n0 + tx + 16*j;
    float bias;
    if (MODE==0) bias = (col < 3072) ? B0[col] : B1[col-3072];
    else         bias = B0[col];
    #pragma unroll
    for (int i=0;i<4;i++){
      const int m = m0 + ty*4 + i;
      const float v = acc[i][j] + bias;
      if (MODE==0){
        const int tok = m >> 2, bb = m & 3;   // A row = tok*B + b
        if (col < 3072){
          const int which = col >> 10, e = col & 1023;
          const int h = e >> 6, d = e & 63;
          const size_t off = ((size_t)(bb*16+h)*NTOK + tok)*64 + d;
          if      (which==0) Qo[off] = v*0.125f;  // * d^-0.5
          else if (which==1) Ko[off] = v;
          else               Vo[off] = v;
        } else {
          const int j2 = col - 3072;            // rel col = nb*16 + h
          const int h = j2 & 15, nb = j2 >> 4;
          VALS[((size_t)(bb*16+h)*NTOK + tok)*32 + nb] = v;
        }
      } else {
        OUT[(size_t)m*EMB + col] = v;
      }
    }
  }
}

// ---------------------------------------------------------------------------
// Attention: streams = {main, ngram0, ngram1} x 64 (b,h).
// All streams attend causally to main keys u<=t; ngram streams add exactly
// one extra key at token qtok (= T + n*T + t), bucket f(0). Softmax without
// max-subtraction (scores bounded, fp32 exp exact enough): l=sum exp.
// Bucket LUT fs[n]=bucket(n) staged from the input arrays (no float-log).
// Block: 256 thr = 4 waves; each thread owns one query row; block jb owns
// stripes {0,1,6,7} (jb=0) / {2,3,4,5} (jb=1) -> equal triangular work.
// k/v tiles (64 tok x 64 d fp32) staged in LDS (broadcast reads).
// ---------------------------------------------------------------------------
__global__ __launch_bounds__(256)
void attn_k(const float* __restrict__ Q,
            const float* __restrict__ K,
            const float* __restrict__ V,
            const float* __restrict__ VALS,
            const int* __restrict__ IBM,
            const int* __restrict__ IBN,
            float* __restrict__ OUT)
{
  __shared__ float ks[64*64];
  __shared__ float vs[64*64];
  __shared__ int fs[516];

  const int blk = blockIdx.x;
  const int jb = blk & 1, sbh = blk >> 1;
  const int stream = sbh >> 6, bh = sbh & 63;
  const int tid = threadIdx.x, w = tid >> 6, lane = tid & 63;
  const int stripe = (jb == 0) ? ((w < 2) ? w : w + 4) : (w + 2);
  const int t = stripe*64 + lane;
  const int qtok = t + stream*T_LEN;

  // bucket LUT from inputs: IBM[0][n][0] = bucket(n), IBN[0][511][0] = bucket(512)
  fs[tid]       = IBM[(size_t)tid * T_LEN];
  fs[tid + 256] = IBM[(size_t)(tid + 256) * T_LEN];
  if (tid == 0) fs[512] = IBN[(size_t)511 * (2*T_LEN)];

  float q[64], o[64];
  {
    const float* qrow = Q + ((size_t)bh*NTOK + qtok)*64;
    #pragma unroll
    for (int i=0;i<16;i++) *(float4*)&q[i*4] = *(const float4*)(qrow + i*4);
  }
  #pragma unroll
  for (int d=0; d<64; d++) o[d]=0.f;
  float l = 0.f;
  const float* vrow = VALS + ((size_t)bh*NTOK + qtok)*32;
  const int relofs = (stream > 0) ? 1 : 0;   // ngram key_pos = pos-1
  const int numTiles = (jb == 0) ? 8 : 6;
  const int tmaxw = stripe*64 + 63;
  const int sr = tid >> 2, sc2 = (tid & 3) * 16;
  __syncthreads();

  for (int tile = 0; tile < numTiles; ++tile) {
    const int u0 = tile * 64;
    { // cooperative stage of k/v tile
      const float* krow = K + ((size_t)bh*NTOK + u0 + sr)*64 + sc2;
      const float* vr2  = V + ((size_t)bh*NTOK + u0 + sr)*64 + sc2;
      #pragma unroll
      for (int c=0;c<4;c++){
        *(float4*)&ks[sr*64+sc2+c*4] = *(const float4*)(krow + c*4);
        *(float4*)&vs[sr*64+sc2+c*4] = *(const float4*)(vr2 + c*4);
      }
    }
    __syncthreads();
    if (u0 <= tmaxw) {
      int uumax = t - u0 + 1; if (uumax > 64) uumax = 64;
      for (int uu = 0; uu < uumax; ++uu) {
        const float* kr = &ks[uu*64];
        float s0=0.f,s1=0.f,s2=0.f,s3=0.f;
        #pragma unroll
        for (int d=0; d<64; d+=4) {
          float4 k4 = *(const float4*)(kr + d);
          s0 += q[d]*k4.x; s1 += q[d+1]*k4.y; s2 += q[d+2]*k4.z; s3 += q[d+3]*k4.w;
        }
        const int nd = t - (u0+uu) + relofs;
        const float rel = vrow[fs[nd]];
        const float p = __expf(((s0+s1)+(s2+s3)) + rel);
        l += p;
        const float* vr = &vs[uu*64];
        #pragma unroll
        for (int d=0; d<64; d+=4) {
          float4 v4 = *(const float4*)(vr + d);
          o[d] += p*v4.x; o[d+1] += p*v4.y; o[d+2] += p*v4.z; o[d+3] += p*v4.w;
        }
      }
    }
    __syncthreads();
  }

  if (stream > 0) { // the single allowed ngram key: token qtok, bucket f(0)
    const float* krow = K + ((size_t)bh*NTOK + qtok)*64;
    const float* vr2  = V + ((size_t)bh*NTOK + qtok)*64;
    float s = 0.f;
    #pragma unroll
    for (int d=0; d<64; d++) s += q[d]*krow[d];
    const float p = __expf(s + vrow[fs[0]]);
    l += p;
    #pragma unroll
    for (int d=0; d<64; d++) o[d] += p*vr2[d];
  }

  const float inv = 1.0f / l;
  float* orow = OUT + ((size_t)qtok*BS + (bh>>4))*EMB + (bh&15)*64;
  #pragma unroll
  for (int d=0; d<64; d+=4){
    float4 r; r.x=o[d]*inv; r.y=o[d+1]*inv; r.z=o[d+2]*inv; r.w=o[d+3]*inv;
    *(float4*)(orow + d) = r;
  }
}

// ---------------------------------------------------------------------------
extern "C" void kernel_launch(void* const* d_in, const int* in_sizes, int n_in,
                              void* d_out, int out_size, void* d_ws, size_t ws_size,
                              hipStream_t stream) {
  (void)in_sizes; (void)n_in; (void)out_size; (void)ws_size;
  const float* hidden = (const float*)d_in[0];
  const float* wqkv   = (const float*)d_in[1];
  const float* bqkv   = (const float*)d_in[2];
  const float* relw   = (const float*)d_in[3];
  const float* relb   = (const float*)d_in[4];
  const float* outw   = (const float*)d_in[5];
  const float* outb   = (const float*)d_in[6];
  // d_in[7] self_attn_mask / d_in[8] ngram_mask: reproduced analytically
  const int* ibm = (const int*)d_in[9];
  const int* ibn = (const int*)d_in[10];

  // workspace layout (fp32, all 16B aligned):
  //  Q,K,V: [64 bh][1536 tok][64 d]       (25.2 MB each)
  //  ATT:   [6144 rows][1024]             (25.2 MB)
  //  VALS:  [64 bh][1536 tok][32 buckets] (12.6 MB)   total ~113 MB
  float* Qb  = (float*)d_ws;
  float* Kb  = Qb + (size_t)64*NTOK*64;
  float* Vb  = Kb + (size_t)64*NTOK*64;
  float* ATT = Vb + (size_t)64*NTOK*64;
  float* VLS = ATT + (size_t)6144*EMB;

  gemm_k<0><<<dim3(56, 96), 256, 0, stream>>>(hidden, wqkv, relw, bqkv, relb,
                                              Qb, Kb, Vb, VLS, nullptr);
  attn_k<<<384, 256, 0, stream>>>(Qb, Kb, Vb, VLS, ibm, ibn, ATT);
  gemm_k<1><<<dim3(16, 96), 256, 0, stream>>>(ATT, outw, nullptr, outb, nullptr,
                                              nullptr, nullptr, nullptr, nullptr,
                                              (float*)d_out);
}

// Round 3
// 840.570 us; speedup vs baseline: 1.8259x; 1.8259x over previous
//
#include <hip/hip_runtime.h>
#include <stdint.h>

#define T_LEN 512
#define NTOK  1536   // (1+NGRAM)*T
#define EMB   1024
#define BS    4

typedef __bf16 bf16x8 __attribute__((ext_vector_type(8)));
typedef float  f32x4  __attribute__((ext_vector_type(4)));

__device__ __forceinline__ unsigned short f2bf(float f){
  union { float f; unsigned int i; } v; v.f = f;
  unsigned int x = v.i;
  return (unsigned short)((x + 0x7fffu + ((x >> 16) & 1u)) >> 16); // RNE
}

__device__ __forceinline__ void gld_lds16(const unsigned short* gptr, unsigned short* lptr){
  __builtin_amdgcn_global_load_lds(
      (const __attribute__((address_space(1))) unsigned int*)gptr,
      (__attribute__((address_space(3))) unsigned int*)lptr, 16, 0, 0);
}

// ---------------------------------------------------------------------------
// fp32 -> bf16 cast pre-pass. Segments (elements):
//   hidden 6291456 -> Hb ; wqkv 3145728 -> Wc[0..) ; relw 524288 -> Wc[3145728..)
//   outw 1048576 -> Ob.  8 elems/thread, 16B stores. Memory-bound (~15us).
// ---------------------------------------------------------------------------
__global__ __launch_bounds__(256)
void cast_k(const float* __restrict__ h, const float* __restrict__ wq,
            const float* __restrict__ rw, const float* __restrict__ ow,
            unsigned short* __restrict__ Hb, unsigned short* __restrict__ Wc,
            unsigned short* __restrict__ Ob)
{
  const size_t e = ((size_t)blockIdx.x * 256 + threadIdx.x) * 8;
  const float* src; unsigned short* dst;
  if (e < 6291456)            { src = h  + e;                 dst = Hb + e; }
  else if (e < 9437184)       { size_t o = e - 6291456;       src = wq + o; dst = Wc + o; }
  else if (e < 9961472)       { size_t o = e - 9437184;       src = rw + o; dst = Wc + 3145728 + o; }
  else                        { size_t o = e - 9961472;       src = ow + o; dst = Ob + o; }
  float4 f0 = *(const float4*)src, f1 = *(const float4*)(src + 4);
  unsigned short r[8];
  r[0]=f2bf(f0.x); r[1]=f2bf(f0.y); r[2]=f2bf(f0.z); r[3]=f2bf(f0.w);
  r[4]=f2bf(f1.x); r[5]=f2bf(f1.y); r[6]=f2bf(f1.z); r[7]=f2bf(f1.w);
  *(uint4*)dst = *(const uint4*)r;
}

// ---------------------------------------------------------------------------
// bf16 MFMA GEMM (m97 recipe): C[m,n] = sum_k A[m,k]*W[n,k] (+bias epilogue).
// 128x128 block tile, BK=32, 256 thr = 2x2 waves, each wave 64x64 via 4x4
// mfma_f32_16x16x32_bf16. Staging via global_load_lds width=16: LDS rows of
// 32 bf16 (64B) unpadded; wave-uniform LDS base + lane*16 == row lane/4,
// chunk lane%4 (m104 caveat respected).
// MODE 0: A=Hb(6144x1024), W=Wc(3584x1024: 3072 qkv + 512 rel). Epilogue
//   scatters q(x0.125)/k/v -> fp32 [bh][tok][64] and rel-vals -> fp32
//   [bh][tok][32].
// MODE 1: A=ATTb(6144x1024 bf16), W=Ob(outw), +outb -> fp32 d_out.
// ---------------------------------------------------------------------------
template<int MODE>
__global__ __launch_bounds__(256)
void mgemm(const unsigned short* __restrict__ A,
           const unsigned short* __restrict__ W,
           const float* __restrict__ B0,
           const float* __restrict__ B1,
           float* __restrict__ Qo, float* __restrict__ Ko,
           float* __restrict__ Vo, float* __restrict__ VALS,
           float* __restrict__ OUT)
{
  __shared__ unsigned short As[128*32];
  __shared__ unsigned short Bs[128*32];
  const int K = 1024;
  const int m0 = blockIdx.y * 128, n0 = blockIdx.x * 128;
  const int tid = threadIdx.x;
  const int wid = tid >> 6, lane = tid & 63;
  const int wm = wid >> 1, wn = wid & 1;
  const int srow = lane >> 2, schunk = (lane & 3) * 8;

  f32x4 acc[4][4];
  #pragma unroll
  for (int i=0;i<4;i++)
    #pragma unroll
    for (int j=0;j<4;j++)
      #pragma unroll
      for (int r=0;r<4;r++) acc[i][j][r] = 0.f;

  const int l15 = lane & 15, q8 = (lane >> 4) * 8;

  for (int k0 = 0; k0 < K; k0 += 32) {
    #pragma unroll
    for (int p = 0; p < 2; ++p) {
      const int r0 = p*64 + wid*16;
      gld_lds16(A + (size_t)(m0 + r0 + srow)*K + k0 + schunk, &As[r0*32]);
      gld_lds16(W + (size_t)(n0 + r0 + srow)*K + k0 + schunk, &Bs[r0*32]);
    }
    __syncthreads();
    bf16x8 af[4], bf[4];
    #pragma unroll
    for (int i=0;i<4;i++) af[i] = *(const bf16x8*)&As[(wm*64 + i*16 + l15)*32 + q8];
    #pragma unroll
    for (int j=0;j<4;j++) bf[j] = *(const bf16x8*)&Bs[(wn*64 + j*16 + l15)*32 + q8];
    #pragma unroll
    for (int i=0;i<4;i++)
      #pragma unroll
      for (int j=0;j<4;j++)
        acc[i][j] = __builtin_amdgcn_mfma_f32_16x16x32_bf16(af[i], bf[j], acc[i][j], 0, 0, 0);
    __syncthreads();
  }

  // epilogue: C/D layout col=lane&15, row=(lane>>4)*4+reg
  const int rbase = (lane >> 4) * 4;
  #pragma unroll
  for (int j=0;j<4;j++){
    const int col = n0 + wn*64 + j*16 + l15;
    float bias;
    if (MODE==0) bias = (col < 3072) ? B0[col] : B1[col-3072];
    else         bias = B0[col];
    #pragma unroll
    for (int i=0;i<4;i++){
      #pragma unroll
      for (int r=0;r<4;r++){
        const int m = m0 + wm*64 + i*16 + rbase + r;
        const float v = acc[i][j][r] + bias;
        if (MODE==0){
          const int tok = m >> 2, bb = m & 3;        // A row = tok*B + b
          if (col < 3072){
            const int which = col >> 10, e = col & 1023;
            const int h = e >> 6, d = e & 63;
            const size_t off = ((size_t)(bb*16+h)*NTOK + tok)*64 + d;
            if      (which==0) Qo[off] = v*0.125f;   // * d^-0.5
            else if (which==1) Ko[off] = v;
            else               Vo[off] = v;
          } else {
            const int j2 = col - 3072;               // rel col = nb*16 + h
            const int h = j2 & 15, nb = j2 >> 4;
            VALS[((size_t)(bb*16+h)*NTOK + tok)*32 + nb] = v;
          }
        } else {
          OUT[(size_t)m*EMB + col] = v;
        }
      }
    }
  }
}

// ---------------------------------------------------------------------------
// Attention (unchanged math, fp32; output now bf16 for the MODE1 MFMA GEMM).
// streams = {main, ngram0, ngram1} x 64 (b,h); causal over main keys u<=t,
// ngram streams add exactly one extra key at token qtok, bucket f(0).
// Softmax without max-subtraction (scores bounded). Bucket LUT from inputs.
// ---------------------------------------------------------------------------
__global__ __launch_bounds__(256)
void attn_k(const float* __restrict__ Q,
            const float* __restrict__ K,
            const float* __restrict__ V,
            const float* __restrict__ VALS,
            const int* __restrict__ IBM,
            const int* __restrict__ IBN,
            unsigned short* __restrict__ OUT)
{
  __shared__ float ks[64*64];
  __shared__ float vs[64*64];
  __shared__ int fs[516];

  const int blk = blockIdx.x;
  const int jb = blk & 1, sbh = blk >> 1;
  const int stream = sbh >> 6, bh = sbh & 63;
  const int tid = threadIdx.x, w = tid >> 6, lane = tid & 63;
  const int stripe = (jb == 0) ? ((w < 2) ? w : w + 4) : (w + 2);
  const int t = stripe*64 + lane;
  const int qtok = t + stream*T_LEN;

  fs[tid]       = IBM[(size_t)tid * T_LEN];
  fs[tid + 256] = IBM[(size_t)(tid + 256) * T_LEN];
  if (tid == 0) fs[512] = IBN[(size_t)511 * (2*T_LEN)];

  float q[64], o[64];
  {
    const float* qrow = Q + ((size_t)bh*NTOK + qtok)*64;
    #pragma unroll
    for (int i=0;i<16;i++) *(float4*)&q[i*4] = *(const float4*)(qrow + i*4);
  }
  #pragma unroll
  for (int d=0; d<64; d++) o[d]=0.f;
  float l = 0.f;
  const float* vrow = VALS + ((size_t)bh*NTOK + qtok)*32;
  const int relofs = (stream > 0) ? 1 : 0;   // ngram key_pos = pos-1
  const int numTiles = (jb == 0) ? 8 : 6;
  const int tmaxw = stripe*64 + 63;
  const int sr = tid >> 2, sc2 = (tid & 3) * 16;
  __syncthreads();

  for (int tile = 0; tile < numTiles; ++tile) {
    const int u0 = tile * 64;
    {
      const float* krow = K + ((size_t)bh*NTOK + u0 + sr)*64 + sc2;
      const float* vr2  = V + ((size_t)bh*NTOK + u0 + sr)*64 + sc2;
      #pragma unroll
      for (int c=0;c<4;c++){
        *(float4*)&ks[sr*64+sc2+c*4] = *(const float4*)(krow + c*4);
        *(float4*)&vs[sr*64+sc2+c*4] = *(const float4*)(vr2 + c*4);
      }
    }
    __syncthreads();
    if (u0 <= tmaxw) {
      int uumax = t - u0 + 1; if (uumax > 64) uumax = 64;
      for (int uu = 0; uu < uumax; ++uu) {
        const float* kr = &ks[uu*64];
        float s0=0.f,s1=0.f,s2=0.f,s3=0.f;
        #pragma unroll
        for (int d=0; d<64; d+=4) {
          float4 k4 = *(const float4*)(kr + d);
          s0 += q[d]*k4.x; s1 += q[d+1]*k4.y; s2 += q[d+2]*k4.z; s3 += q[d+3]*k4.w;
        }
        const int nd = t - (u0+uu) + relofs;
        const float rel = vrow[fs[nd]];
        const float p = __expf(((s0+s1)+(s2+s3)) + rel);
        l += p;
        const float* vr = &vs[uu*64];
        #pragma unroll
        for (int d=0; d<64; d+=4) {
          float4 v4 = *(const float4*)(vr + d);
          o[d] += p*v4.x; o[d+1] += p*v4.y; o[d+2] += p*v4.z; o[d+3] += p*v4.w;
        }
      }
    }
    __syncthreads();
  }

  if (stream > 0) {
    const float* krow = K + ((size_t)bh*NTOK + qtok)*64;
    const float* vr2  = V + ((size_t)bh*NTOK + qtok)*64;
    float s = 0.f;
    #pragma unroll
    for (int d=0; d<64; d++) s += q[d]*krow[d];
    const float p = __expf(s + vrow[fs[0]]);
    l += p;
    #pragma unroll
    for (int d=0; d<64; d++) o[d] += p*vr2[d];
  }

  const float inv = 1.0f / l;
  unsigned short* orow = OUT + ((size_t)qtok*BS + (bh>>4))*EMB + (bh&15)*64;
  #pragma unroll
  for (int d=0; d<64; d+=2){
    unsigned int pk = (unsigned int)f2bf(o[d]*inv)
                    | ((unsigned int)f2bf(o[d+1]*inv) << 16);
    *(unsigned int*)(orow + d) = pk;
  }
}

// ---------------------------------------------------------------------------
extern "C" void kernel_launch(void* const* d_in, const int* in_sizes, int n_in,
                              void* d_out, int out_size, void* d_ws, size_t ws_size,
                              hipStream_t stream) {
  (void)in_sizes; (void)n_in; (void)out_size; (void)ws_size;
  const float* hidden = (const float*)d_in[0];
  const float* wqkv   = (const float*)d_in[1];
  const float* bqkv   = (const float*)d_in[2];
  const float* relw   = (const float*)d_in[3];
  const float* relb   = (const float*)d_in[4];
  const float* outw   = (const float*)d_in[5];
  const float* outb   = (const float*)d_in[6];
  const int* ibm = (const int*)d_in[9];
  const int* ibn = (const int*)d_in[10];

  // workspace (~105 MB):
  //  Hb  bf16 6291456   (hidden cast; later reused as ATTb — Hb is dead after mgemm<0>)
  //  Wc  bf16 3670016   (wqkv rows ++ relw rows)
  //  Ob  bf16 1048576   (outw)
  //  Qf/Kf/Vf fp32 [64 bh][1536 tok][64]  (25.2 MB each)
  //  VALS fp32 [64 bh][1536 tok][32]      (12.6 MB)
  unsigned short* Hb = (unsigned short*)d_ws;
  unsigned short* Wc = Hb + (size_t)6291456;
  unsigned short* Ob = Wc + (size_t)3670016;
  float* Qf  = (float*)(Ob + (size_t)1048576);
  float* Kf  = Qf + (size_t)64*NTOK*64;
  float* Vf  = Kf + (size_t)64*NTOK*64;
  float* VLS = Vf + (size_t)64*NTOK*64;
  unsigned short* ATTb = Hb;  // alias: hidden-bf16 dead once mgemm<0> completes

  cast_k<<<5376, 256, 0, stream>>>(hidden, wqkv, relw, outw, Hb, Wc, Ob);
  mgemm<0><<<dim3(28, 48), 256, 0, stream>>>(Hb, Wc, bqkv, relb,
                                             Qf, Kf, Vf, VLS, nullptr);
  attn_k<<<384, 256, 0, stream>>>(Qf, Kf, Vf, VLS, ibm, ibn, ATTb);
  mgemm<1><<<dim3(8, 48), 256, 0, stream>>>(ATTb, Ob, outb, nullptr,
                                            nullptr, nullptr, nullptr, nullptr,
                                            (float*)d_out);
}

// Round 4
// 331.326 us; speedup vs baseline: 4.6322x; 2.5370x over previous
//
#include <hip/hip_runtime.h>
#include <stdint.h>

#define T_LEN 512
#define NTOK  1536   // (1+NGRAM)*T
#define EMB   1024
#define BS    4

typedef __bf16 bf16x8 __attribute__((ext_vector_type(8)));
typedef float  f32x4  __attribute__((ext_vector_type(4)));

__device__ __forceinline__ float bflo(unsigned short u){
  union { unsigned int i; float f; } a; a.i = ((unsigned int)u) << 16; return a.f;
}
__device__ __forceinline__ unsigned short f2bf(float f){
  union { float f; unsigned int i; } v; v.f = f;
  unsigned int x = v.i;
  return (unsigned short)((x + 0x7fffu + ((x >> 16) & 1u)) >> 16); // RNE
}

__device__ __forceinline__ void gld_lds16(const unsigned short* gptr, unsigned short* lptr){
  __builtin_amdgcn_global_load_lds(
      (const __attribute__((address_space(1))) unsigned int*)gptr,
      (__attribute__((address_space(3))) unsigned int*)lptr, 16, 0, 0);
}

// ---------------------------------------------------------------------------
// fp32 -> bf16 cast pre-pass (hidden, wqkv++relw, outw). 8 elems/thread.
// ---------------------------------------------------------------------------
__global__ __launch_bounds__(256)
void cast_k(const float* __restrict__ h, const float* __restrict__ wq,
            const float* __restrict__ rw, const float* __restrict__ ow,
            unsigned short* __restrict__ Hb, unsigned short* __restrict__ Wc,
            unsigned short* __restrict__ Ob)
{
  const size_t e = ((size_t)blockIdx.x * 256 + threadIdx.x) * 8;
  const float* src; unsigned short* dst;
  if (e < 6291456)            { src = h  + e;                 dst = Hb + e; }
  else if (e < 9437184)       { size_t o = e - 6291456;       src = wq + o; dst = Wc + o; }
  else if (e < 9961472)       { size_t o = e - 9437184;       src = rw + o; dst = Wc + 3145728 + o; }
  else                        { size_t o = e - 9961472;       src = ow + o; dst = Ob + o; }
  float4 f0 = *(const float4*)src, f1 = *(const float4*)(src + 4);
  unsigned short r[8];
  r[0]=f2bf(f0.x); r[1]=f2bf(f0.y); r[2]=f2bf(f0.z); r[3]=f2bf(f0.w);
  r[4]=f2bf(f1.x); r[5]=f2bf(f1.y); r[6]=f2bf(f1.z); r[7]=f2bf(f1.w);
  *(uint4*)dst = *(const uint4*)r;
}

// ---------------------------------------------------------------------------
// bf16 MFMA GEMM (m97 recipe), 128x128 tile, BK=32, 2x2 waves x 4x4 frags.
// MODE 0: A=Hb(6144x1024), W=Wc(3584 rows: 3072 qkv + 512 rel). Epilogue:
//   Q (x0.125) -> bf16 [bh][tok][64]; K -> bf16 [bh][tok][64];
//   V -> bf16 TRANSPOSED [bh][d][tok]; rel-vals -> fp32 [bh][tok][32].
// MODE 1: A=ATTb bf16, W=Ob(outw), +outb -> fp32 d_out.
// ---------------------------------------------------------------------------
template<int MODE>
__global__ __launch_bounds__(256)
void mgemm(const unsigned short* __restrict__ A,
           const unsigned short* __restrict__ W,
           const float* __restrict__ B0,
           const float* __restrict__ B1,
           unsigned short* __restrict__ Qo, unsigned short* __restrict__ Ko,
           unsigned short* __restrict__ Vo, float* __restrict__ VALS,
           float* __restrict__ OUT)
{
  __shared__ unsigned short As[128*32];
  __shared__ unsigned short Bs[128*32];
  const int K = 1024;
  const int m0 = blockIdx.y * 128, n0 = blockIdx.x * 128;
  const int tid = threadIdx.x;
  const int wid = tid >> 6, lane = tid & 63;
  const int wm = wid >> 1, wn = wid & 1;
  const int srow = lane >> 2, schunk = (lane & 3) * 8;

  f32x4 acc[4][4];
  #pragma unroll
  for (int i=0;i<4;i++)
    #pragma unroll
    for (int j=0;j<4;j++)
      #pragma unroll
      for (int r=0;r<4;r++) acc[i][j][r] = 0.f;

  const int l15 = lane & 15, q8 = (lane >> 4) * 8;

  for (int k0 = 0; k0 < K; k0 += 32) {
    #pragma unroll
    for (int p = 0; p < 2; ++p) {
      const int r0 = p*64 + wid*16;
      gld_lds16(A + (size_t)(m0 + r0 + srow)*K + k0 + schunk, &As[r0*32]);
      gld_lds16(W + (size_t)(n0 + r0 + srow)*K + k0 + schunk, &Bs[r0*32]);
    }
    __syncthreads();
    bf16x8 af[4], bf[4];
    #pragma unroll
    for (int i=0;i<4;i++) af[i] = *(const bf16x8*)&As[(wm*64 + i*16 + l15)*32 + q8];
    #pragma unroll
    for (int j=0;j<4;j++) bf[j] = *(const bf16x8*)&Bs[(wn*64 + j*16 + l15)*32 + q8];
    #pragma unroll
    for (int i=0;i<4;i++)
      #pragma unroll
      for (int j=0;j<4;j++)
        acc[i][j] = __builtin_amdgcn_mfma_f32_16x16x32_bf16(af[i], bf[j], acc[i][j], 0, 0, 0);
    __syncthreads();
  }

  const int rbase = (lane >> 4) * 4;
  #pragma unroll
  for (int j=0;j<4;j++){
    const int col = n0 + wn*64 + j*16 + l15;
    float bias;
    if (MODE==0) bias = (col < 3072) ? B0[col] : B1[col-3072];
    else         bias = B0[col];
    #pragma unroll
    for (int i=0;i<4;i++){
      #pragma unroll
      for (int r=0;r<4;r++){
        const int m = m0 + wm*64 + i*16 + rbase + r;
        const float v = acc[i][j][r] + bias;
        if (MODE==0){
          const int tok = m >> 2, bb = m & 3;        // A row = tok*B + b
          if (col < 3072){
            const int which = col >> 10, e = col & 1023;
            const int h = e >> 6, d = e & 63;
            const int bh = bb*16 + h;
            if      (which==0) Qo[((size_t)bh*NTOK + tok)*64 + d] = f2bf(v*0.125f);
            else if (which==1) Ko[((size_t)bh*NTOK + tok)*64 + d] = f2bf(v);
            else               Vo[((size_t)bh*64 + d)*NTOK + tok] = f2bf(v); // V^T
          } else {
            const int j2 = col - 3072;               // rel col = nb*16 + h
            const int h = j2 & 15, nb = j2 >> 4;
            VALS[((size_t)(bb*16+h)*NTOK + tok)*32 + nb] = v;
          }
        } else {
          OUT[(size_t)m*EMB + col] = v;
        }
      }
    }
  }
}

// ---------------------------------------------------------------------------
// MFMA flash attention. Block = (stream, bh, qi): 64 q-rows; 4 waves x 16 rows.
// Per key-tile (64 main keys, causal):
//   S^T = mfma(A=K, B=Q): lane holds (key=16i+4*q4+r, q=l15).
//   p = (u<=t) ? exp(s + VALS[q][bucket(t-u+ofs)]) : 0  (no max-subtraction;
//   scores bounded). P -> per-wave LDS [16 q][64 key] bf16 (b64-packed along
//   the 4 consecutive key regs; row pad 72 keeps b128 reads 16B-aligned).
//   O += mfma(A=P, B=V^T): lane holds (q=4*q4+r, d=16jd+l15).
// l = in-register row sums + shfl_xor(16,32). Ngram streams add exactly one
// extra key at token qtok (bucket fs[0]) via a scalar tail.
// ---------------------------------------------------------------------------
__global__ __launch_bounds__(256)
void fattn(const unsigned short* __restrict__ Q,
           const unsigned short* __restrict__ K,
           const unsigned short* __restrict__ VT,
           const float* __restrict__ VALS,
           const int* __restrict__ IBM,
           const int* __restrict__ IBN,
           unsigned short* __restrict__ OUT)
{
  __shared__ unsigned short Pl[4][16*72];
  __shared__ float vls[64*33];
  __shared__ int fs[513];
  __shared__ float pex[4][16];
  __shared__ float lar[4][16];

  const int blk = blockIdx.x;
  const int qi = blk & 7, sbh = blk >> 3;
  const int stream = sbh >> 6, bh = sbh & 63;
  const int tid = threadIdx.x, wid = tid >> 6, lane = tid & 63;
  const int l15 = lane & 15, q4 = lane >> 4;
  const int tokbase = stream*T_LEN + qi*64;
  const int relofs = (stream > 0) ? 1 : 0;

  // stage bucket LUT (bucket(n) at IBM[0][n][0]; bucket(512) at IBN[0][511][0])
  fs[tid]       = IBM[(size_t)tid * T_LEN];
  fs[tid + 256] = IBM[(size_t)(tid + 256) * T_LEN];
  if (tid == 0) fs[512] = IBN[(size_t)511 * (2*T_LEN)];
  // stage VALS tile: 64 q-rows x 32 buckets, row pad 33 (conflict-free)
  {
    const int row = tid >> 2, c8 = (tid & 3) * 8;
    const float* vsrc = VALS + ((size_t)bh*NTOK + tokbase + row)*32 + c8;
    *(float4*)&vls[row*33 + c8]     = *(const float4*)vsrc;
    *(float4*)&vls[row*33 + c8 + 4] = *(const float4*)(vsrc + 4);
  }

  const int t = qi*64 + wid*16 + l15;          // this lane's q row (S^T stage)
  const int qtok_l = tokbase + wid*16 + l15;

  bf16x8 bq[2];
  {
    const unsigned short* qp = Q + ((size_t)bh*NTOK + qtok_l)*64 + q4*8;
    bq[0] = *(const bf16x8*)qp;
    bq[1] = *(const bf16x8*)(qp + 32);
  }

  f32x4 o[4];
  #pragma unroll
  for (int jd=0;jd<4;jd++)
    #pragma unroll
    for (int r=0;r<4;r++) o[jd][r] = 0.f;
  float lreg = 0.f;
  const f32x4 zero = {0.f,0.f,0.f,0.f};
  unsigned short* Pw = &Pl[wid][0];

  __syncthreads();

  const int ntiles = qi + 1;
  for (int tile = 0; tile < ntiles; ++tile) {
    const int u0 = tile * 64;
    // S^T = K . Q^T  (A=K rows=keys, B=Q rows=queries), direct global frags
    f32x4 st[4];
    #pragma unroll
    for (int i=0;i<4;i++){
      const unsigned short* kp = K + ((size_t)bh*NTOK + u0 + 16*i + l15)*64 + q4*8;
      bf16x8 a0 = *(const bf16x8*)kp;
      bf16x8 a1 = *(const bf16x8*)(kp + 32);
      st[i] = __builtin_amdgcn_mfma_f32_16x16x32_bf16(a0, bq[0], zero, 0, 0, 0);
      st[i] = __builtin_amdgcn_mfma_f32_16x16x32_bf16(a1, bq[1], st[i], 0, 0, 0);
    }
    // mask + rel + exp; pack P -> LDS; partial row sums
    float lp = 0.f;
    #pragma unroll
    for (int i=0;i<4;i++){
      unsigned short pr4[4];
      #pragma unroll
      for (int r=0;r<4;r++){
        const int u = u0 + 16*i + q4*4 + r;
        const bool ok = (u <= t);
        const int nd = ok ? (t - u + relofs) : 0;
        const float rel = vls[(wid*16 + l15)*33 + fs[nd]];
        float p = ok ? __expf(st[i][r] + rel) : 0.f;
        const unsigned short pb = f2bf(p);
        pr4[r] = pb;
        lp += bflo(pb);            // l from the rounded P (consistent with PV)
      }
      uint2 pk;
      pk.x = (unsigned int)pr4[0] | ((unsigned int)pr4[1] << 16);
      pk.y = (unsigned int)pr4[2] | ((unsigned int)pr4[3] << 16);
      *(uint2*)&Pw[l15*72 + 16*i + q4*4] = pk;
    }
    lp += __shfl_xor(lp, 16);
    lp += __shfl_xor(lp, 32);
    lreg += lp;
    // O += P . V   (A=P from LDS, B=V^T rows=dims from global)
    bf16x8 ap0 = *(const bf16x8*)&Pw[l15*72 + q4*8];
    bf16x8 ap1 = *(const bf16x8*)&Pw[l15*72 + 32 + q4*8];
    #pragma unroll
    for (int jd=0;jd<4;jd++){
      const unsigned short* vp = VT + ((size_t)bh*64 + 16*jd + l15)*NTOK + u0 + q4*8;
      bf16x8 b0 = *(const bf16x8*)vp;
      bf16x8 b1 = *(const bf16x8*)(vp + 32);
      o[jd] = __builtin_amdgcn_mfma_f32_16x16x32_bf16(ap0, b0, o[jd], 0, 0, 0);
      o[jd] = __builtin_amdgcn_mfma_f32_16x16x32_bf16(ap1, b1, o[jd], 0, 0, 0);
    }
  }

  // ngram streams: single extra key at token qtok (bucket fs[0])
  if (stream > 0) {
    const unsigned short* qp2 = Q + ((size_t)bh*NTOK + qtok_l)*64 + q4*16;
    const unsigned short* kp2 = K + ((size_t)bh*NTOK + qtok_l)*64 + q4*16;
    float s = 0.f;
    #pragma unroll
    for (int c=0;c<2;c++){
      bf16x8 qv = *(const bf16x8*)(qp2 + c*8);
      bf16x8 kv = *(const bf16x8*)(kp2 + c*8);
      #pragma unroll
      for (int e=0;e<8;e++) s += (float)qv[e] * (float)kv[e];
    }
    s += __shfl_xor(s, 16);
    s += __shfl_xor(s, 32);
    const float p = __expf(s + vls[(wid*16 + l15)*33 + fs[0]]);
    lreg += p;
    pex[wid][l15] = p;
    __syncthreads();
    #pragma unroll
    for (int r=0;r<4;r++){
      const int qloc = q4*4 + r;
      const float pq = pex[wid][qloc];
      const int qtk = tokbase + wid*16 + qloc;
      #pragma unroll
      for (int jd=0;jd<4;jd++){
        const float vv = bflo(VT[((size_t)bh*64 + 16*jd + l15)*NTOK + qtk]);
        o[jd][r] += pq * vv;
      }
    }
  }

  lar[wid][l15] = lreg;
  __syncthreads();

  const int b = bh >> 4, h = bh & 15;
  #pragma unroll
  for (int r=0;r<4;r++){
    const int qloc = q4*4 + r;
    const float inv = 1.0f / lar[wid][qloc];
    const int qtk = tokbase + wid*16 + qloc;
    unsigned short* orow = OUT + ((size_t)qtk*BS + b)*EMB + h*64 + l15;
    #pragma unroll
    for (int jd=0;jd<4;jd++)
      orow[16*jd] = f2bf(o[jd][r] * inv);
  }
}

// ---------------------------------------------------------------------------
extern "C" void kernel_launch(void* const* d_in, const int* in_sizes, int n_in,
                              void* d_out, int out_size, void* d_ws, size_t ws_size,
                              hipStream_t stream) {
  (void)in_sizes; (void)n_in; (void)out_size; (void)ws_size;
  const float* hidden = (const float*)d_in[0];
  const float* wqkv   = (const float*)d_in[1];
  const float* bqkv   = (const float*)d_in[2];
  const float* relw   = (const float*)d_in[3];
  const float* relb   = (const float*)d_in[4];
  const float* outw   = (const float*)d_in[5];
  const float* outb   = (const float*)d_in[6];
  const int* ibm = (const int*)d_in[9];
  const int* ibn = (const int*)d_in[10];

  // workspace (~68 MB):
  //  Hb bf16 6291456 (hidden cast; reused as ATTb after mgemm<0>)
  //  Wc bf16 3670016 ; Ob bf16 1048576
  //  Qb/Kb bf16 [64 bh][1536 tok][64] ; VTb bf16 [64 bh][64 d][1536 tok]
  //  VALS fp32 [64 bh][1536 tok][32]
  unsigned short* Hb  = (unsigned short*)d_ws;
  unsigned short* Wc  = Hb + (size_t)6291456;
  unsigned short* Ob  = Wc + (size_t)3670016;
  unsigned short* Qb  = Ob + (size_t)1048576;
  unsigned short* Kb  = Qb + (size_t)6291456;
  unsigned short* VTb = Kb + (size_t)6291456;
  float* VLS = (float*)(VTb + (size_t)6291456);
  unsigned short* ATTb = Hb;   // alias: hidden-bf16 dead after mgemm<0>

  cast_k<<<5376, 256, 0, stream>>>(hidden, wqkv, relw, outw, Hb, Wc, Ob);
  mgemm<0><<<dim3(28, 48), 256, 0, stream>>>(Hb, Wc, bqkv, relb,
                                             Qb, Kb, VTb, VLS, nullptr);
  fattn<<<1536, 256, 0, stream>>>(Qb, Kb, VTb, VLS, ibm, ibn, ATTb);
  mgemm<1><<<dim3(8, 48), 256, 0, stream>>>(ATTb, Ob, outb, nullptr,
                                            nullptr, nullptr, nullptr, nullptr,
                                            (float*)d_out);
}